// Round 14
// baseline (375.052 us; speedup 1.0000x reference)
//
#include <hip/hip_runtime.h>
#include <hip/hip_bf16.h>
#include <hip/hip_fp16.h>

// Problem constants
#define TB 128
#define TT 500
#define TS 200
#define TE 100
#define TH 100
#define NCLS 400              // 2*S  (one-hot width of x)
#define NG   400              // 4*H  (gate width)
#define BT   (TB*TT)          // 64000 (b,t) pairs
#define BLK  256              // 4 waves x 7 tile-slots (dups write-masked)

typedef _Float16 h8 __attribute__((ext_vector_type(8)));
union HU { float4 f4; __half hs[8]; };

__device__ __forceinline__ float frcp(float x) { return __builtin_amdgcn_rcpf(x); }
__device__ __forceinline__ float fsig(float x) { return frcp(1.f + __expf(-x)); }
__device__ __forceinline__ float ftanh(float x) { float e = __expf(2.f * x); return 1.f - 2.f * frcp(e + 1.f); }

// LDS-only barrier: drain lgkm (ds ops) but leave global loads/stores in flight.
__device__ __forceinline__ void barrier_lds() {
  asm volatile("s_waitcnt lgkmcnt(0)\n\ts_barrier" ::: "memory");
}

// quad-perm DPP cross-lane (within aligned 4-lane quads): ~VALU-speed, no LDS.
#define QXOR1(d, s) d = __int_as_float(__builtin_amdgcn_mov_dpp(__float_as_int(s), 177, 0xf, 0xf, true)) // [1,0,3,2]
#define QXOR2(d, s) d = __int_as_float(__builtin_amdgcn_mov_dpp(__float_as_int(s),  78, 0xf, 0xf, true)) // [2,3,0,1]
#define QXOR3(d, s) d = __int_as_float(__builtin_amdgcn_mov_dpp(__float_as_int(s),  27, 0xf, 0xf, true)) // [3,2,1,0]

// ---------------------------------------------------------------------------
// Kernel A: compress one-hot x (B,T,400) -> idx2 and q (B,T,200) -> qi.
// ---------------------------------------------------------------------------
__global__ void k_compress(const float* __restrict__ x, const float* __restrict__ q,
                           int* __restrict__ idx2, int* __restrict__ qi) {
  int gid  = blockIdx.x * blockDim.x + threadIdx.x;
  int wave = gid >> 6;
  int lane = threadIdx.x & 63;
  if (wave >= BT) return;

  const float4* xr = (const float4*)(x + (size_t)wave * NCLS);
  int li = -1;
  {
    float4 v = xr[lane];
    if (v.x > 0.5f) li = lane * 4 + 0;
    if (v.y > 0.5f) li = lane * 4 + 1;
    if (v.z > 0.5f) li = lane * 4 + 2;
    if (v.w > 0.5f) li = lane * 4 + 3;
    int ci = 64 + lane;
    if (ci < 100) {
      float4 w = xr[ci];
      if (w.x > 0.5f) li = ci * 4 + 0;
      if (w.y > 0.5f) li = ci * 4 + 1;
      if (w.z > 0.5f) li = ci * 4 + 2;
      if (w.w > 0.5f) li = ci * 4 + 3;
    }
  }
  #pragma unroll
  for (int off = 32; off; off >>= 1) li = max(li, __shfl_xor(li, off));

  const float4* qr = (const float4*)(q + (size_t)wave * TS);
  int qj = -1;
  if (lane < 50) {
    float4 v = qr[lane];
    if (v.x > 0.5f) qj = lane * 4 + 0;
    if (v.y > 0.5f) qj = lane * 4 + 1;
    if (v.z > 0.5f) qj = lane * 4 + 2;
    if (v.w > 0.5f) qj = lane * 4 + 3;
  }
  #pragma unroll
  for (int off = 32; off; off >>= 1) qj = max(qj, __shfl_xor(qj, off));

  if (lane == 0) { idx2[wave] = li; qi[wave] = qj; }
}

// ---------------------------------------------------------------------------
// Kernel A2: count features, fully parallel (one block per b, thread t).
// ---------------------------------------------------------------------------
__global__ void k_counts(const int* __restrict__ idx2, float2* __restrict__ ccg) {
  __shared__ int ids[TT];
  int b = blockIdx.x, tid = threadIdx.x;
  for (int i = tid; i < TT; i += 512) ids[i] = idx2[(size_t)b * TT + i];
  __syncthreads();
  if (tid < TT) {
    int s2 = ids[tid] & ~1;
    int c0 = 0, c1 = 0;
    for (int tp = 0; tp <= tid; ++tp) {
      int v = ids[tp];
      c0 += (v == s2);
      c1 += (v == s2 + 1);
    }
    ccg[(size_t)b * TT + tid] =
        make_float2(__logf(1.f + (float)c0), __logf(1.f + (float)c1));
  }
}

// ---------------------------------------------------------------------------
// Kernel B: precompute permuted tables for the MFMA layout.
// Permutation: orig gate-col j = g*100+u  ->  cp = (u>>2)*16 + (u&3)*4 + g
//  Gq[cls][cp], baseq/c0q/c1q[cp]  (f32)
//  Bfrag[(tile*4+ks)*64 + lane] = float4 of 8 f16: R[k][col(cp)] with
//     k = ks*32 + (lane>>4)*8 + j  (zero-pad k>=100), cp = tile*16+(lane&15)
//  WoT[s][k] = Wo[k][s]
// ---------------------------------------------------------------------------
__global__ void k_precompute(const float* __restrict__ Wx, const float* __restrict__ bx,
                             const float* __restrict__ K, const float* __restrict__ lb,
                             const float* __restrict__ Wo, const float* __restrict__ R,
                             float* __restrict__ Gq, float* __restrict__ baseq,
                             float* __restrict__ c0q, float* __restrict__ c1q,
                             float* __restrict__ WoT, float4* __restrict__ Bfrag) {
  int bid = blockIdx.x, tid = threadIdx.x;
  if (bid < NCLS) {
    if (tid < NG) {
      float acc = 0.0f;
      for (int e = 0; e < TE; ++e) acc = fmaf(Wx[bid * TE + e], K[e * NG + tid], acc);
      int g = tid / 100, u = tid % 100;
      int cp = (u >> 2) * 16 + (u & 3) * 4 + g;
      Gq[bid * NG + cp] = acc;
    }
  } else if (bid == NCLS) {
    if (tid < NG) {
      float acc = lb[tid];
      for (int e = 0; e < TE; ++e) acc = fmaf(bx[e], K[e * NG + tid], acc);
      int g = tid / 100, u = tid % 100;
      int cp = (u >> 2) * 16 + (u & 3) * 4 + g;
      baseq[cp] = acc;
      c0q[cp]   = K[100 * NG + tid] + K[102 * NG + tid];
      c1q[cp]   = K[101 * NG + tid] + K[102 * NG + tid];
    }
  } else {
    int id = (bid - NCLS - 1) * 512 + tid;
    if (id < TS * TH) {
      int s = id / TH, k = id % TH;
      WoT[id] = Wo[k * TS + s];
    } else {
      int id2 = id - TS * TH;
      if (id2 < 6400) {
        int lane = id2 & 63, ks = (id2 >> 6) & 3, tile = id2 >> 8;
        int qq = lane & 15, cgrp = lane >> 4;
        int col = (qq & 3) * 100 + tile * 4 + (qq >> 2);   // orig R column
        HU uu;
        #pragma unroll
        for (int j = 0; j < 8; ++j) {
          int k = ks * 32 + cgrp * 8 + j;
          float v = (k < TH) ? R[k * NG + col] : 0.0f;
          uu.hs[j] = __float2half_rn(v);
        }
        Bfrag[id2] = uu.f4;
      }
    }
  }
}

// ---------------------------------------------------------------------------
// Kernel C: LSTM recurrence, MATRIX pipe, ONE batch element per block (the
// R11 structure — R13's 2-elem M-split kept per-CU DS cost, doubled VALU,
// added bank conflicts, and idled CUs: wall time is 500 x per-step critical
// path, so only the step length matters).
// R14 change: 4 waves (256 thr) x 7 tile-slots instead of 7 waves x 4 —
// DS-pipe reads drop 28 -> 16 instr/step, MFMA issue is 1 wave/SIMD,
// barrier rendezvous is 4 waves. Slots s=0..6 of wave w compute tiles
// min(6w+s, 24); write ownership partitions 0..24 exactly once:
//   slotA = cg   -> tile 6w+cg (always owned)
//   slotB = 4+cg -> tile 6w+4+cg, owned iff cg<2 (w<3) or cg<3 (w==3)
// AGPR map (clobber-reserved): B-frag slot s, ks: a[16s+4ks .. +3] (a0-a111,
// written once); acc slot s: a[112+4s .. +3] (a112-a139); zero a[140:143].
// Broadcast-A (all C rows equal, read reg0) per R10/R11-validated layout.
// ONE lgkm-only barrier/step; h in 2-row f16 LDS dbuf; G/cc prefetch depth-2.
// ---------------------------------------------------------------------------
#define AW(N, V) asm volatile("v_accvgpr_write_b32 a" #N ", %0" :: "v"(V) : "a" #N)
#define AW4(N0,N1,N2,N3, F) do { AW(N0,(F).x); AW(N1,(F).y); AW(N2,(F).z); AW(N3,(F).w); } while(0)

#define CLOBS \
  "a0","a1","a2","a3","a4","a5","a6","a7","a8","a9","a10","a11","a12","a13", \
  "a14","a15","a16","a17","a18","a19","a20","a21","a22","a23","a24","a25",   \
  "a26","a27","a28","a29","a30","a31","a32","a33","a34","a35","a36","a37",   \
  "a38","a39","a40","a41","a42","a43","a44","a45","a46","a47","a48","a49",   \
  "a50","a51","a52","a53","a54","a55","a56","a57","a58","a59","a60","a61",   \
  "a62","a63","a64","a65","a66","a67","a68","a69","a70","a71","a72","a73",   \
  "a74","a75","a76","a77","a78","a79","a80","a81","a82","a83","a84","a85",   \
  "a86","a87","a88","a89","a90","a91","a92","a93","a94","a95","a96","a97",   \
  "a98","a99","a100","a101","a102","a103","a104","a105","a106","a107",       \
  "a108","a109","a110","a111","a112","a113","a114","a115","a116","a117",     \
  "a118","a119","a120","a121","a122","a123","a124","a125","a126","a127",     \
  "a128","a129","a130","a131","a132","a133","a134","a135","a136","a137",     \
  "a138","a139","a140","a141","a142","a143"

// 28 MFMAs: 7 slots x 4 K-subtiles, interleaved so each acc quad's writes
// are 7 issues apart (pipelined). Reads: reg0 of each acc quad.
#define MFMA28(Z0,Z1,Z2,Z3,Z4,Z5,Z6, FA0,FA1,FA2,FA3)                \
  asm volatile(                                                       \
    "s_nop 1\n\t"                                                     \
    "v_mfma_f32_16x16x32_f16 a[112:115], %7, a[0:3],    a[140:143]\n\t" \
    "v_mfma_f32_16x16x32_f16 a[116:119], %7, a[16:19],  a[140:143]\n\t" \
    "v_mfma_f32_16x16x32_f16 a[120:123], %7, a[32:35],  a[140:143]\n\t" \
    "v_mfma_f32_16x16x32_f16 a[124:127], %7, a[48:51],  a[140:143]\n\t" \
    "v_mfma_f32_16x16x32_f16 a[128:131], %7, a[64:67],  a[140:143]\n\t" \
    "v_mfma_f32_16x16x32_f16 a[132:135], %7, a[80:83],  a[140:143]\n\t" \
    "v_mfma_f32_16x16x32_f16 a[136:139], %7, a[96:99],  a[140:143]\n\t" \
    "v_mfma_f32_16x16x32_f16 a[112:115], %8, a[4:7],    a[112:115]\n\t" \
    "v_mfma_f32_16x16x32_f16 a[116:119], %8, a[20:23],  a[116:119]\n\t" \
    "v_mfma_f32_16x16x32_f16 a[120:123], %8, a[36:39],  a[120:123]\n\t" \
    "v_mfma_f32_16x16x32_f16 a[124:127], %8, a[52:55],  a[124:127]\n\t" \
    "v_mfma_f32_16x16x32_f16 a[128:131], %8, a[68:71],  a[128:131]\n\t" \
    "v_mfma_f32_16x16x32_f16 a[132:135], %8, a[84:87],  a[132:135]\n\t" \
    "v_mfma_f32_16x16x32_f16 a[136:139], %8, a[100:103],a[136:139]\n\t" \
    "v_mfma_f32_16x16x32_f16 a[112:115], %9, a[8:11],   a[112:115]\n\t" \
    "v_mfma_f32_16x16x32_f16 a[116:119], %9, a[24:27],  a[116:119]\n\t" \
    "v_mfma_f32_16x16x32_f16 a[120:123], %9, a[40:43],  a[120:123]\n\t" \
    "v_mfma_f32_16x16x32_f16 a[124:127], %9, a[56:59],  a[124:127]\n\t" \
    "v_mfma_f32_16x16x32_f16 a[128:131], %9, a[72:75],  a[128:131]\n\t" \
    "v_mfma_f32_16x16x32_f16 a[132:135], %9, a[88:91],  a[132:135]\n\t" \
    "v_mfma_f32_16x16x32_f16 a[136:139], %9, a[104:107],a[136:139]\n\t" \
    "v_mfma_f32_16x16x32_f16 a[112:115], %10, a[12:15], a[112:115]\n\t" \
    "v_mfma_f32_16x16x32_f16 a[116:119], %10, a[28:31], a[116:119]\n\t" \
    "v_mfma_f32_16x16x32_f16 a[120:123], %10, a[44:47], a[120:123]\n\t" \
    "v_mfma_f32_16x16x32_f16 a[124:127], %10, a[60:63], a[124:127]\n\t" \
    "v_mfma_f32_16x16x32_f16 a[128:131], %10, a[76:79], a[128:131]\n\t" \
    "v_mfma_f32_16x16x32_f16 a[132:135], %10, a[92:95], a[132:135]\n\t" \
    "v_mfma_f32_16x16x32_f16 a[136:139], %10, a[108:111],a[136:139]\n\t" \
    "v_accvgpr_read_b32 %0, a112\n\t"                                 \
    "v_accvgpr_read_b32 %1, a116\n\t"                                 \
    "v_accvgpr_read_b32 %2, a120\n\t"                                 \
    "v_accvgpr_read_b32 %3, a124\n\t"                                 \
    "v_accvgpr_read_b32 %4, a128\n\t"                                 \
    "s_nop 7\n\ts_nop 7\n\t"                                          \
    "v_accvgpr_read_b32 %5, a132\n\t"                                 \
    "v_accvgpr_read_b32 %6, a136"                                     \
    : "=v"(Z0), "=v"(Z1), "=v"(Z2), "=v"(Z3), "=v"(Z4), "=v"(Z5), "=v"(Z6) \
    : "v"(FA0), "v"(FA1), "v"(FA2), "v"(FA3)                          \
    : CLOBS)

__global__ void __attribute__((amdgpu_flat_work_group_size(BLK, BLK)))
k_lstm(const int* __restrict__ idx2, const float* __restrict__ Gq,
       const float* __restrict__ baseq, const float* __restrict__ c0q,
       const float* __restrict__ c1q, const float4* __restrict__ Bfrag,
       const float2* __restrict__ ccg, float* __restrict__ h_seq) {
  __shared__ __align__(16) __half hbuf[2][128];   // padded h rows (k>=100 stay 0)
  __shared__ int idx_ls[TT];

  int b = blockIdx.x, tid = threadIdx.x;
  int w = tid >> 6, lane = tid & 63;
  int q = lane & 15, g3 = lane & 3, cg = lane >> 4, qd = (lane >> 2) & 3;

  for (int i = tid; i < TT; i += BLK) idx_ls[i] = idx2[(size_t)b * TT + i];
  { __half* hb = &hbuf[0][0];
    for (int i = tid; i < 256; i += BLK) hb[i] = __float2half(0.f); }

  // 7 tile slots per wave (clamped dups computed, write-masked)
  int t0 = min(6 * w + 0, 24), t1 = min(6 * w + 1, 24), t2 = min(6 * w + 2, 24);
  int t3 = min(6 * w + 3, 24), t4 = min(6 * w + 4, 24), t5 = min(6 * w + 5, 24);
  int t6 = min(6 * w + 6, 24);

  // lane's two activation slots: A = cg (tile 6w+cg, always owned),
  // B = 4+cg (tile 6w+4+cg, owned iff cg<2, or cg<3 when w==3)
  int tileA = 6 * w + cg;                        // <= 21, always valid
  int tileBu = 6 * w + 4 + cg;                   // unclamped
  int tileB = min(tileBu, 24);
  int gcolA = tileA * 16 + q, gcolB = tileB * 16 + q;
  float baseA = baseq[gcolA], c0A = c0q[gcolA], c1A = c1q[gcolA];
  float baseB = baseq[gcolB], c0B = c0q[gcolB], c1B = c1q[gcolB];
  int uA = tileA * 4 + qd, uB = tileB * 4 + qd;
  bool ownB = (w == 3) ? (cg < 3) : (cg < 2);
  bool wrA = (g3 == 0);
  bool wrB = (g3 == 0) && ownB;

  // ---- load B fragments into AGPRs (once) ----
  {
    float4 f;
    f = Bfrag[(t0 * 4 + 0) * 64 + lane]; AW4(0,1,2,3, f);
    f = Bfrag[(t0 * 4 + 1) * 64 + lane]; AW4(4,5,6,7, f);
    f = Bfrag[(t0 * 4 + 2) * 64 + lane]; AW4(8,9,10,11, f);
    f = Bfrag[(t0 * 4 + 3) * 64 + lane]; AW4(12,13,14,15, f);
    f = Bfrag[(t1 * 4 + 0) * 64 + lane]; AW4(16,17,18,19, f);
    f = Bfrag[(t1 * 4 + 1) * 64 + lane]; AW4(20,21,22,23, f);
    f = Bfrag[(t1 * 4 + 2) * 64 + lane]; AW4(24,25,26,27, f);
    f = Bfrag[(t1 * 4 + 3) * 64 + lane]; AW4(28,29,30,31, f);
    f = Bfrag[(t2 * 4 + 0) * 64 + lane]; AW4(32,33,34,35, f);
    f = Bfrag[(t2 * 4 + 1) * 64 + lane]; AW4(36,37,38,39, f);
    f = Bfrag[(t2 * 4 + 2) * 64 + lane]; AW4(40,41,42,43, f);
    f = Bfrag[(t2 * 4 + 3) * 64 + lane]; AW4(44,45,46,47, f);
    f = Bfrag[(t3 * 4 + 0) * 64 + lane]; AW4(48,49,50,51, f);
    f = Bfrag[(t3 * 4 + 1) * 64 + lane]; AW4(52,53,54,55, f);
    f = Bfrag[(t3 * 4 + 2) * 64 + lane]; AW4(56,57,58,59, f);
    f = Bfrag[(t3 * 4 + 3) * 64 + lane]; AW4(60,61,62,63, f);
    f = Bfrag[(t4 * 4 + 0) * 64 + lane]; AW4(64,65,66,67, f);
    f = Bfrag[(t4 * 4 + 1) * 64 + lane]; AW4(68,69,70,71, f);
    f = Bfrag[(t4 * 4 + 2) * 64 + lane]; AW4(72,73,74,75, f);
    f = Bfrag[(t4 * 4 + 3) * 64 + lane]; AW4(76,77,78,79, f);
    f = Bfrag[(t5 * 4 + 0) * 64 + lane]; AW4(80,81,82,83, f);
    f = Bfrag[(t5 * 4 + 1) * 64 + lane]; AW4(84,85,86,87, f);
    f = Bfrag[(t5 * 4 + 2) * 64 + lane]; AW4(88,89,90,91, f);
    f = Bfrag[(t5 * 4 + 3) * 64 + lane]; AW4(92,93,94,95, f);
    f = Bfrag[(t6 * 4 + 0) * 64 + lane]; AW4(96,97,98,99, f);
    f = Bfrag[(t6 * 4 + 1) * 64 + lane]; AW4(100,101,102,103, f);
    f = Bfrag[(t6 * 4 + 2) * 64 + lane]; AW4(104,105,106,107, f);
    f = Bfrag[(t6 * 4 + 3) * 64 + lane]; AW4(108,109,110,111, f);
    float zf = 0.0f;
    AW(140, zf); AW(141, zf); AW(142, zf); AW(143, zf);
  }
  asm volatile("" ::: CLOBS);    // a0..a143 reserved for the whole kernel

  float c_regA = 0.f, c_regB = 0.f;
  __syncthreads();               // idx_ls, hbuf visible

  const float2* ccg_b = ccg + (size_t)b * TT;
  float* hout = h_seq + (size_t)b * TT * TH;

  // prefetch depth 2
  float gA1 = Gq[(size_t)idx_ls[0] * NG + gcolA];
  float gA2 = Gq[(size_t)idx_ls[0] * NG + gcolB];
  float gB1 = Gq[(size_t)idx_ls[1] * NG + gcolA];
  float gB2 = Gq[(size_t)idx_ls[1] * NG + gcolB];
  float2 ccA = ccg_b[0], ccB = ccg_b[1];

  #define ACT(ZZ, CREG, HN)                                                    \
  { float arg = (g3 == 2) ? ((ZZ) + (ZZ)) : (-(ZZ));                           \
    float E = __expf(arg);                                                     \
    float r = frcp(1.f + E);                                                   \
    float act = (g3 == 2) ? fmaf(-2.f, r, 1.f) : r;                            \
    float x1, x2, x3;                                                          \
    QXOR1(x1, act); QXOR2(x2, act); QXOR3(x3, act);                            \
    (CREG) = fmaf(x1, (CREG), act * x2);   /* g3==0 lanes: ai=act af=x1 ag=x2 */\
    (HN) = x3 * ftanh(CREG); }

  #define STEP(T_, PAR, G1, G2, CCV)                                           \
  { const int t_ = (T_);                                                       \
    barrier_lds();               /* h(t-1) visible; VMEM stays in flight */    \
    const h8* hrow = (const h8*)(&hbuf[(PAR) ^ 1][0]);                         \
    h8 fa0 = hrow[cg], fa1 = hrow[4 + cg], fa2 = hrow[8 + cg], fa3 = hrow[12 + cg]; \
    float z0, z1, z2, z3, z4, z5, z6;                                          \
    MFMA28(z0, z1, z2, z3, z4, z5, z6, fa0, fa1, fa2, fa3);                    \
    float zA = (cg == 0) ? z0 : (cg == 1) ? z1 : (cg == 2) ? z2 : z3;          \
    float zB = (cg == 0) ? z4 : (cg == 1) ? z5 : z6;                           \
    float2 cc = (CCV);                                                         \
    int tnx = (t_ + 2 < TT) ? t_ + 2 : TT - 1;                                 \
    float zzA = zA + (G1) + baseA + cc.x * c0A + cc.y * c1A;                   \
    float zzB = zB + (G2) + baseB + cc.x * c0B + cc.y * c1B;                   \
    int idn = idx_ls[tnx];                                                     \
    (G1) = Gq[(size_t)idn * NG + gcolA];         /* depth-2 refill */          \
    (G2) = Gq[(size_t)idn * NG + gcolB];                                       \
    (CCV) = ccg_b[tnx];                                                        \
    float hnA, hnB;                                                            \
    ACT(zzA, c_regA, hnA);                                                     \
    ACT(zzB, c_regB, hnB);                                                     \
    if (wrA) {                                                                 \
      hbuf[PAR][uA] = __float2half_rn(hnA);                                    \
      hout[(size_t)t_ * TH + uA] = hnA;          /* un-drained store */        \
    }                                                                          \
    if (wrB) {                                                                 \
      hbuf[PAR][uB] = __float2half_rn(hnB);                                    \
      hout[(size_t)t_ * TH + uB] = hnB;                                        \
    }                                                                          \
  }

  for (int t2p = 0; t2p < TT; t2p += 2) {
    STEP(t2p, 0, gA1, gA2, ccA);      // even t: read hbuf[1], write hbuf[0]
    STEP(t2p + 1, 1, gB1, gB2, ccB);  // odd  t: read hbuf[0], write hbuf[1]
  }
  #undef STEP
  #undef ACT
}

// ---------------------------------------------------------------------------
// Kernel D: out[b,t] = sigmoid( h_seq[b,t] . WoT[qi[b,t]] + bo[qi] )
// ---------------------------------------------------------------------------
__global__ void k_out(const float* __restrict__ h_seq, const float* __restrict__ WoT,
                      const float* __restrict__ bo, const int* __restrict__ qi,
                      float* __restrict__ out) {
  int gid  = blockIdx.x * blockDim.x + threadIdx.x;
  int wave = gid >> 6;
  int lane = threadIdx.x & 63;
  if (wave >= BT) return;
  int s = qi[wave];
  const float4* h4 = (const float4*)(h_seq + (size_t)wave * TH);
  const float4* w4 = (const float4*)(WoT + (size_t)s * TH);
  float acc = 0.0f;
  if (lane < TH / 4) {
    float4 h = h4[lane];
    float4 w = w4[lane];
    acc = h.x * w.x + h.y * w.y + h.z * w.z + h.w * w.w;
  }
  #pragma unroll
  for (int off = 32; off; off >>= 1) acc += __shfl_xor(acc, off);
  if (lane == 0) out[wave] = fsig(acc + bo[s]);
}

// ---------------------------------------------------------------------------
extern "C" void kernel_launch(void* const* d_in, const int* in_sizes, int n_in,
                              void* d_out, int out_size, void* d_ws, size_t ws_size,
                              hipStream_t stream) {
  const float* x    = (const float*)d_in[0];
  // d_in[1] = delta (unused by the reference)
  const float* q    = (const float*)d_in[2];
  const float* Wx   = (const float*)d_in[3];
  const float* bx   = (const float*)d_in[4];
  const float* K    = (const float*)d_in[5];   // lstm_k (103,400)
  const float* R    = (const float*)d_in[6];   // lstm_rk (100,400)
  const float* lb   = (const float*)d_in[7];   // lstm_b (400)
  const float* Wo   = (const float*)d_in[8];   // (100,200)
  const float* bo   = (const float*)d_in[9];   // (200)
  float* out = (float*)d_out;

  // workspace layout (floats)
  float* ws = (float*)d_ws;
  float*  Gq     = ws;                      // 160000
  float*  baseq  = ws + 160000;             // 400
  float*  c0q    = ws + 160400;             // 400
  float*  c1q    = ws + 160800;             // 400
  float*  WoT    = ws + 161200;             // 20000
  float4* Bfrag  = (float4*)(ws + 181200);  // 6400 float4 = 25600 floats
  int*    idx2   = (int*)(ws + 206800);     // 64000
  int*    qi     = (int*)(ws + 270800);     // 64000
  float2* ccg    = (float2*)(ws + 334800);  // 64000 float2 = 128000 floats
  float*  h_seq  = ws + 462800;             // 6,400,000
  // total: 6,862,800 floats = 27.5 MB

  // A: compress one-hots
  k_compress<<<BT / 4, 256, 0, stream>>>(x, q, idx2, qi);

  // A2: parallel count features
  k_counts<<<TB, 512, 0, stream>>>(idx2, ccg);

  // B: precompute permuted tables + MFMA B-fragments
  int tail_blocks = (TS * TH + 6400 + 511) / 512;        // 52
  k_precompute<<<NCLS + 1 + tail_blocks, 512, 0, stream>>>(Wx, bx, K, lb, Wo, R,
                                                           Gq, baseq, c0q, c1q, WoT, Bfrag);

  // C: sequential LSTM, one block per batch element, 4-wave MFMA recurrence
  k_lstm<<<TB, BLK, 0, stream>>>(idx2, Gq, baseq, c0q, c1q, Bfrag, ccg, h_seq);

  // D: gather + dot + sigmoid
  k_out<<<BT / 4, 256, 0, stream>>>(h_seq, WoT, bo, qi, out);
}

// Round 16
// 284.988 us; speedup vs baseline: 1.3160x; 1.3160x over previous
//
#include <hip/hip_runtime.h>
#include <hip/hip_bf16.h>
#include <hip/hip_fp16.h>

// Problem constants
#define TB 128
#define TT 500
#define TS 200
#define TE 100
#define TH 100
#define NCLS 400              // 2*S  (one-hot width of x)
#define NG   400              // 4*H  (gate width)
#define BT   (TB*TT)          // 64000 (b,t) pairs
#define BLK  512              // 8 waves: waves 0-6 own tiles 3w..3w+2, wave 7 owns 21..24

typedef _Float16 h8 __attribute__((ext_vector_type(8)));
union HU { float4 f4; __half hs[8]; };

__device__ __forceinline__ float frcp(float x) { return __builtin_amdgcn_rcpf(x); }
__device__ __forceinline__ float fsig(float x) { return frcp(1.f + __expf(-x)); }
__device__ __forceinline__ float ftanh(float x) { float e = __expf(2.f * x); return 1.f - 2.f * frcp(e + 1.f); }

// LDS-only barrier: drain lgkm (ds ops) but leave global loads/stores in flight.
__device__ __forceinline__ void barrier_lds() {
  asm volatile("s_waitcnt lgkmcnt(0)\n\ts_barrier" ::: "memory");
}

// quad-perm DPP cross-lane (within aligned 4-lane quads): ~VALU-speed, no LDS.
#define QXOR1(d, s) d = __int_as_float(__builtin_amdgcn_mov_dpp(__float_as_int(s), 177, 0xf, 0xf, true)) // [1,0,3,2]
#define QXOR2(d, s) d = __int_as_float(__builtin_amdgcn_mov_dpp(__float_as_int(s),  78, 0xf, 0xf, true)) // [2,3,0,1]
#define QXOR3(d, s) d = __int_as_float(__builtin_amdgcn_mov_dpp(__float_as_int(s),  27, 0xf, 0xf, true)) // [3,2,1,0]

// ---------------------------------------------------------------------------
// Kernel A: compress one-hot x (B,T,400) -> idx2 and q (B,T,200) -> qi.
// ---------------------------------------------------------------------------
__global__ void k_compress(const float* __restrict__ x, const float* __restrict__ q,
                           int* __restrict__ idx2, int* __restrict__ qi) {
  int gid  = blockIdx.x * blockDim.x + threadIdx.x;
  int wave = gid >> 6;
  int lane = threadIdx.x & 63;
  if (wave >= BT) return;

  const float4* xr = (const float4*)(x + (size_t)wave * NCLS);
  int li = -1;
  {
    float4 v = xr[lane];
    if (v.x > 0.5f) li = lane * 4 + 0;
    if (v.y > 0.5f) li = lane * 4 + 1;
    if (v.z > 0.5f) li = lane * 4 + 2;
    if (v.w > 0.5f) li = lane * 4 + 3;
    int ci = 64 + lane;
    if (ci < 100) {
      float4 w = xr[ci];
      if (w.x > 0.5f) li = ci * 4 + 0;
      if (w.y > 0.5f) li = ci * 4 + 1;
      if (w.z > 0.5f) li = ci * 4 + 2;
      if (w.w > 0.5f) li = ci * 4 + 3;
    }
  }
  #pragma unroll
  for (int off = 32; off; off >>= 1) li = max(li, __shfl_xor(li, off));

  const float4* qr = (const float4*)(q + (size_t)wave * TS);
  int qj = -1;
  if (lane < 50) {
    float4 v = qr[lane];
    if (v.x > 0.5f) qj = lane * 4 + 0;
    if (v.y > 0.5f) qj = lane * 4 + 1;
    if (v.z > 0.5f) qj = lane * 4 + 2;
    if (v.w > 0.5f) qj = lane * 4 + 3;
  }
  #pragma unroll
  for (int off = 32; off; off >>= 1) qj = max(qj, __shfl_xor(qj, off));

  if (lane == 0) { idx2[wave] = li; qi[wave] = qj; }
}

// ---------------------------------------------------------------------------
// Kernel A2: count features, fully parallel (one block per b, thread t).
// ---------------------------------------------------------------------------
__global__ void k_counts(const int* __restrict__ idx2, float2* __restrict__ ccg) {
  __shared__ int ids[TT];
  int b = blockIdx.x, tid = threadIdx.x;
  for (int i = tid; i < TT; i += 512) ids[i] = idx2[(size_t)b * TT + i];
  __syncthreads();
  if (tid < TT) {
    int s2 = ids[tid] & ~1;
    int c0 = 0, c1 = 0;
    for (int tp = 0; tp <= tid; ++tp) {
      int v = ids[tp];
      c0 += (v == s2);
      c1 += (v == s2 + 1);
    }
    ccg[(size_t)b * TT + tid] =
        make_float2(__logf(1.f + (float)c0), __logf(1.f + (float)c1));
  }
}

// ---------------------------------------------------------------------------
// Kernel B: precompute permuted tables for the MFMA layout.
// Permutation: orig gate-col j = g*100+u  ->  cp = (u>>2)*16 + (u&3)*4 + g
//  Gq[cls][cp], baseq/c0q/c1q[cp]  (f32)
//  Bfrag[(tile*4+ks)*64 + lane] = float4 of 8 f16: R[k][col(cp)] with
//     k = ks*32 + (lane>>4)*8 + j  (zero-pad k>=100), cp = tile*16+(lane&15)
//  WoT[s][k] = Wo[k][s]
// ---------------------------------------------------------------------------
__global__ void k_precompute(const float* __restrict__ Wx, const float* __restrict__ bx,
                             const float* __restrict__ K, const float* __restrict__ lb,
                             const float* __restrict__ Wo, const float* __restrict__ R,
                             float* __restrict__ Gq, float* __restrict__ baseq,
                             float* __restrict__ c0q, float* __restrict__ c1q,
                             float* __restrict__ WoT, float4* __restrict__ Bfrag) {
  int bid = blockIdx.x, tid = threadIdx.x;
  if (bid < NCLS) {
    if (tid < NG) {
      float acc = 0.0f;
      for (int e = 0; e < TE; ++e) acc = fmaf(Wx[bid * TE + e], K[e * NG + tid], acc);
      int g = tid / 100, u = tid % 100;
      int cp = (u >> 2) * 16 + (u & 3) * 4 + g;
      Gq[bid * NG + cp] = acc;
    }
  } else if (bid == NCLS) {
    if (tid < NG) {
      float acc = lb[tid];
      for (int e = 0; e < TE; ++e) acc = fmaf(bx[e], K[e * NG + tid], acc);
      int g = tid / 100, u = tid % 100;
      int cp = (u >> 2) * 16 + (u & 3) * 4 + g;
      baseq[cp] = acc;
      c0q[cp]   = K[100 * NG + tid] + K[102 * NG + tid];
      c1q[cp]   = K[101 * NG + tid] + K[102 * NG + tid];
    }
  } else {
    int id = (bid - NCLS - 1) * 512 + tid;
    if (id < TS * TH) {
      int s = id / TH, k = id % TH;
      WoT[id] = Wo[k * TS + s];
    } else {
      int id2 = id - TS * TH;
      if (id2 < 6400) {
        int lane = id2 & 63, ks = (id2 >> 6) & 3, tile = id2 >> 8;
        int qq = lane & 15, cgrp = lane >> 4;
        int col = (qq & 3) * 100 + tile * 4 + (qq >> 2);   // orig R column
        HU uu;
        #pragma unroll
        for (int j = 0; j < 8; ++j) {
          int k = ks * 32 + cgrp * 8 + j;
          float v = (k < TH) ? R[k * NG + col] : 0.0f;
          uu.hs[j] = __float2half_rn(v);
        }
        Bfrag[id2] = uu.f4;
      }
    }
  }
}

// ---------------------------------------------------------------------------
// Kernel C: LSTM recurrence, MATRIX pipe, ONE elem/block, 8 waves, EXACT-25
// tile partition (no duplicate MFMAs): waves 0-6 -> tiles {3w,3w+1,3w+2}
// (12 MFMA each), wave 7 -> tiles {21,22,23,24} (16 MFMA). SIMDs carry 2
// waves each (latency hiding, the R14 lesson) at 24-28 MFMA of pipe.
// ks-SPLIT asm blocks: 4 MFMA blocks each consuming only fa_k, so the
// compiler emits progressive lgkmcnt waits — MFMA(ks0) starts after ONE
// ds_read, hiding DS latency under the matrix pipe.
// One ACT chain + one G column per lane (halve R11's per-lane VALU).
// AGPR map (clobber-reserved a0-a83): B-frag slot s, ks k: a[16s+4k..+3];
// acc slot s: a[64+4s..+3]; zero quad a[80:83]. Broadcast-A (all C rows
// equal, read reg0) per R10/R11-validated layout. ONE lgkm-only barrier
// per step; h in 2-row f16 LDS dbuf; G/cc prefetch depth-2.
// (R15 compile fix: MK3_3's acc operand typo a[68:31+0] -> a[68:71].)
// ---------------------------------------------------------------------------
#define AW(N, V) asm volatile("v_accvgpr_write_b32 a" #N ", %0" :: "v"(V) : "a" #N)
#define AW4(N0,N1,N2,N3, F) do { AW(N0,(F).x); AW(N1,(F).y); AW(N2,(F).z); AW(N3,(F).w); } while(0)

#define CLOBS \
  "a0","a1","a2","a3","a4","a5","a6","a7","a8","a9","a10","a11","a12","a13", \
  "a14","a15","a16","a17","a18","a19","a20","a21","a22","a23","a24","a25",   \
  "a26","a27","a28","a29","a30","a31","a32","a33","a34","a35","a36","a37",   \
  "a38","a39","a40","a41","a42","a43","a44","a45","a46","a47","a48","a49",   \
  "a50","a51","a52","a53","a54","a55","a56","a57","a58","a59","a60","a61",   \
  "a62","a63","a64","a65","a66","a67","a68","a69","a70","a71","a72","a73",   \
  "a74","a75","a76","a77","a78","a79","a80","a81","a82","a83"

// ks-split MFMA blocks. 4-slot (wave 7) variants:
#define MK0_4(FA) asm volatile("s_nop 1\n\t" \
  "v_mfma_f32_16x16x32_f16 a[64:67], %0, a[0:3],   a[80:83]\n\t" \
  "v_mfma_f32_16x16x32_f16 a[68:71], %0, a[16:19], a[80:83]\n\t" \
  "v_mfma_f32_16x16x32_f16 a[72:75], %0, a[32:35], a[80:83]\n\t" \
  "v_mfma_f32_16x16x32_f16 a[76:79], %0, a[48:51], a[80:83]" :: "v"(FA) : CLOBS)
#define MK1_4(FA) asm volatile("s_nop 1\n\t" \
  "v_mfma_f32_16x16x32_f16 a[64:67], %0, a[4:7],   a[64:67]\n\t" \
  "v_mfma_f32_16x16x32_f16 a[68:71], %0, a[20:23], a[68:71]\n\t" \
  "v_mfma_f32_16x16x32_f16 a[72:75], %0, a[36:39], a[72:75]\n\t" \
  "v_mfma_f32_16x16x32_f16 a[76:79], %0, a[52:55], a[76:79]" :: "v"(FA) : CLOBS)
#define MK2_4(FA) asm volatile("s_nop 1\n\t" \
  "v_mfma_f32_16x16x32_f16 a[64:67], %0, a[8:11],  a[64:67]\n\t" \
  "v_mfma_f32_16x16x32_f16 a[68:71], %0, a[24:27], a[68:71]\n\t" \
  "v_mfma_f32_16x16x32_f16 a[72:75], %0, a[40:43], a[72:75]\n\t" \
  "v_mfma_f32_16x16x32_f16 a[76:79], %0, a[56:59], a[76:79]" :: "v"(FA) : CLOBS)
#define MK3_4(FA) asm volatile("s_nop 1\n\t" \
  "v_mfma_f32_16x16x32_f16 a[64:67], %0, a[12:15], a[64:67]\n\t" \
  "v_mfma_f32_16x16x32_f16 a[68:71], %0, a[28:31], a[68:71]\n\t" \
  "v_mfma_f32_16x16x32_f16 a[72:75], %0, a[44:47], a[72:75]\n\t" \
  "v_mfma_f32_16x16x32_f16 a[76:79], %0, a[60:63], a[76:79]" :: "v"(FA) : CLOBS)
// 3-slot (waves 0-6) variants:
#define MK0_3(FA) asm volatile("s_nop 1\n\t" \
  "v_mfma_f32_16x16x32_f16 a[64:67], %0, a[0:3],   a[80:83]\n\t" \
  "v_mfma_f32_16x16x32_f16 a[68:71], %0, a[16:19], a[80:83]\n\t" \
  "v_mfma_f32_16x16x32_f16 a[72:75], %0, a[32:35], a[80:83]" :: "v"(FA) : CLOBS)
#define MK1_3(FA) asm volatile("s_nop 1\n\t" \
  "v_mfma_f32_16x16x32_f16 a[64:67], %0, a[4:7],   a[64:67]\n\t" \
  "v_mfma_f32_16x16x32_f16 a[68:71], %0, a[20:23], a[68:71]\n\t" \
  "v_mfma_f32_16x16x32_f16 a[72:75], %0, a[36:39], a[72:75]" :: "v"(FA) : CLOBS)
#define MK2_3(FA) asm volatile("s_nop 1\n\t" \
  "v_mfma_f32_16x16x32_f16 a[64:67], %0, a[8:11],  a[64:67]\n\t" \
  "v_mfma_f32_16x16x32_f16 a[68:71], %0, a[24:27], a[68:71]\n\t" \
  "v_mfma_f32_16x16x32_f16 a[72:75], %0, a[40:43], a[72:75]" :: "v"(FA) : CLOBS)
#define MK3_3(FA) asm volatile("s_nop 1\n\t" \
  "v_mfma_f32_16x16x32_f16 a[64:67], %0, a[12:15], a[64:67]\n\t" \
  "v_mfma_f32_16x16x32_f16 a[68:71], %0, a[28:31], a[68:71]\n\t" \
  "v_mfma_f32_16x16x32_f16 a[72:75], %0, a[44:47], a[72:75]" :: "v"(FA) : CLOBS)

#define RD4(Z0,Z1,Z2,Z3) asm volatile( \
  "s_nop 7\n\ts_nop 7\n\ts_nop 7\n\t" \
  "v_accvgpr_read_b32 %0, a64\n\t" \
  "v_accvgpr_read_b32 %1, a68\n\t" \
  "v_accvgpr_read_b32 %2, a72\n\t" \
  "v_accvgpr_read_b32 %3, a76" \
  : "=v"(Z0), "=v"(Z1), "=v"(Z2), "=v"(Z3) :: CLOBS)
#define RD3(Z0,Z1,Z2) asm volatile( \
  "s_nop 7\n\ts_nop 7\n\ts_nop 7\n\t" \
  "v_accvgpr_read_b32 %0, a64\n\t" \
  "v_accvgpr_read_b32 %1, a68\n\t" \
  "v_accvgpr_read_b32 %2, a72" \
  : "=v"(Z0), "=v"(Z1), "=v"(Z2) :: CLOBS)

__global__ void __attribute__((amdgpu_flat_work_group_size(BLK, BLK)))
k_lstm(const int* __restrict__ idx2, const float* __restrict__ Gq,
       const float* __restrict__ baseq, const float* __restrict__ c0q,
       const float* __restrict__ c1q, const float4* __restrict__ Bfrag,
       const float2* __restrict__ ccg, float* __restrict__ h_seq) {
  __shared__ __align__(16) __half hbuf[2][128];   // padded h rows (k>=100 stay 0)
  __shared__ int idx_ls[TT];

  int b = blockIdx.x, tid = threadIdx.x;
  int w = tid >> 6, lane = tid & 63;
  int q = lane & 15, g3 = lane & 3, cg = lane >> 4, qd = (lane >> 2) & 3;

  for (int i = tid; i < TT; i += BLK) idx_ls[i] = idx2[(size_t)b * TT + i];
  { __half* hb = &hbuf[0][0];
    if (tid < 256) hb[tid] = __float2half(0.f); }

  // tile partition (exact 25, no dups): waves 0-6: 3w..3w+2; wave 7: 21..24
  int t0 = (w < 7) ? 3 * w : 21;
  int t1 = t0 + 1, t2 = t0 + 2;
  int t3 = 24;                                   // real slot only on wave 7
  bool own = (w == 7) || (cg < 3);
  int tileA = t0 + ((w == 7) ? cg : min(cg, 2)); // lane's activation tile
  int gcolA = tileA * 16 + q;
  float basej = baseq[gcolA], c0j = c0q[gcolA], c1j = c1q[gcolA];
  int uA = tileA * 4 + qd;
  bool wr = (g3 == 0) && own;

  // ---- load B fragments into AGPRs (once) ----
  {
    float4 f;
    f = Bfrag[(t0 * 4 + 0) * 64 + lane]; AW4(0,1,2,3, f);
    f = Bfrag[(t0 * 4 + 1) * 64 + lane]; AW4(4,5,6,7, f);
    f = Bfrag[(t0 * 4 + 2) * 64 + lane]; AW4(8,9,10,11, f);
    f = Bfrag[(t0 * 4 + 3) * 64 + lane]; AW4(12,13,14,15, f);
    f = Bfrag[(t1 * 4 + 0) * 64 + lane]; AW4(16,17,18,19, f);
    f = Bfrag[(t1 * 4 + 1) * 64 + lane]; AW4(20,21,22,23, f);
    f = Bfrag[(t1 * 4 + 2) * 64 + lane]; AW4(24,25,26,27, f);
    f = Bfrag[(t1 * 4 + 3) * 64 + lane]; AW4(28,29,30,31, f);
    f = Bfrag[(t2 * 4 + 0) * 64 + lane]; AW4(32,33,34,35, f);
    f = Bfrag[(t2 * 4 + 1) * 64 + lane]; AW4(36,37,38,39, f);
    f = Bfrag[(t2 * 4 + 2) * 64 + lane]; AW4(40,41,42,43, f);
    f = Bfrag[(t2 * 4 + 3) * 64 + lane]; AW4(44,45,46,47, f);
    f = Bfrag[(t3 * 4 + 0) * 64 + lane]; AW4(48,49,50,51, f);
    f = Bfrag[(t3 * 4 + 1) * 64 + lane]; AW4(52,53,54,55, f);
    f = Bfrag[(t3 * 4 + 2) * 64 + lane]; AW4(56,57,58,59, f);
    f = Bfrag[(t3 * 4 + 3) * 64 + lane]; AW4(60,61,62,63, f);
    float zf = 0.0f;
    AW(80, zf); AW(81, zf); AW(82, zf); AW(83, zf);
  }
  asm volatile("" ::: CLOBS);    // a0..a83 reserved for the whole kernel

  float c_reg = 0.f;
  __syncthreads();               // idx_ls, hbuf visible

  const float2* ccg_b = ccg + (size_t)b * TT;
  float* hout = h_seq + (size_t)b * TT * TH;

  // prefetch depth 2
  float gA = Gq[(size_t)idx_ls[0] * NG + gcolA];
  float gB = Gq[(size_t)idx_ls[1] * NG + gcolA];
  float2 ccA = ccg_b[0], ccB = ccg_b[1];

  #define ACT(ZZ, CREG, HN)                                                    \
  { float arg = (g3 == 2) ? ((ZZ) + (ZZ)) : (-(ZZ));                           \
    float E = __expf(arg);                                                     \
    float r = frcp(1.f + E);                                                   \
    float act = (g3 == 2) ? fmaf(-2.f, r, 1.f) : r;                            \
    float x1, x2, x3;                                                          \
    QXOR1(x1, act); QXOR2(x2, act); QXOR3(x3, act);                            \
    (CREG) = fmaf(x1, (CREG), act * x2);   /* g3==0 lanes: ai=act af=x1 ag=x2 */\
    (HN) = x3 * ftanh(CREG); }

  #define STEP(T_, PAR, GV, CCV)                                               \
  { const int t_ = (T_);                                                       \
    barrier_lds();               /* h(t-1) visible; VMEM stays in flight */    \
    const h8* hrow = (const h8*)(&hbuf[(PAR) ^ 1][0]);                         \
    h8 fa0 = hrow[cg], fa1 = hrow[4 + cg], fa2 = hrow[8 + cg], fa3 = hrow[12 + cg]; \
    float z0, z1, z2, z3;                                                      \
    if (w == 7) {                                                              \
      MK0_4(fa0); MK1_4(fa1); MK2_4(fa2); MK3_4(fa3);                          \
      RD4(z0, z1, z2, z3);                                                     \
    } else {                                                                   \
      MK0_3(fa0); MK1_3(fa1); MK2_3(fa2); MK3_3(fa3);                          \
      RD3(z0, z1, z2); z3 = z2;                                                \
    }                                                                          \
    float zA = (cg == 0) ? z0 : (cg == 1) ? z1 : (cg == 2) ? z2 : z3;          \
    float2 cc = (CCV);                                                         \
    int tnx = (t_ + 2 < TT) ? t_ + 2 : TT - 1;                                 \
    float zz = zA + (GV) + basej + cc.x * c0j + cc.y * c1j;                    \
    int idn = idx_ls[tnx];                                                     \
    (GV) = Gq[(size_t)idn * NG + gcolA];         /* depth-2 refill */          \
    (CCV) = ccg_b[tnx];                                                        \
    float hn;                                                                  \
    ACT(zz, c_reg, hn);                                                        \
    if (wr) {                                                                  \
      hbuf[PAR][uA] = __float2half_rn(hn);                                     \
      hout[(size_t)t_ * TH + uA] = hn;           /* un-drained store */        \
    }                                                                          \
  }

  for (int t2p = 0; t2p < TT; t2p += 2) {
    STEP(t2p, 0, gA, ccA);      // even t: read hbuf[1], write hbuf[0]
    STEP(t2p + 1, 1, gB, ccB);  // odd  t: read hbuf[0], write hbuf[1]
  }
  #undef STEP
  #undef ACT
}

// ---------------------------------------------------------------------------
// Kernel D: out[b,t] = sigmoid( h_seq[b,t] . WoT[qi[b,t]] + bo[qi] )
// ---------------------------------------------------------------------------
__global__ void k_out(const float* __restrict__ h_seq, const float* __restrict__ WoT,
                      const float* __restrict__ bo, const int* __restrict__ qi,
                      float* __restrict__ out) {
  int gid  = blockIdx.x * blockDim.x + threadIdx.x;
  int wave = gid >> 6;
  int lane = threadIdx.x & 63;
  if (wave >= BT) return;
  int s = qi[wave];
  const float4* h4 = (const float4*)(h_seq + (size_t)wave * TH);
  const float4* w4 = (const float4*)(WoT + (size_t)s * TH);
  float acc = 0.0f;
  if (lane < TH / 4) {
    float4 h = h4[lane];
    float4 w = w4[lane];
    acc = h.x * w.x + h.y * w.y + h.z * w.z + h.w * w.w;
  }
  #pragma unroll
  for (int off = 32; off; off >>= 1) acc += __shfl_xor(acc, off);
  if (lane == 0) out[wave] = fsig(acc + bo[s]);
}

// ---------------------------------------------------------------------------
extern "C" void kernel_launch(void* const* d_in, const int* in_sizes, int n_in,
                              void* d_out, int out_size, void* d_ws, size_t ws_size,
                              hipStream_t stream) {
  const float* x    = (const float*)d_in[0];
  // d_in[1] = delta (unused by the reference)
  const float* q    = (const float*)d_in[2];
  const float* Wx   = (const float*)d_in[3];
  const float* bx   = (const float*)d_in[4];
  const float* K    = (const float*)d_in[5];   // lstm_k (103,400)
  const float* R    = (const float*)d_in[6];   // lstm_rk (100,400)
  const float* lb   = (const float*)d_in[7];   // lstm_b (400)
  const float* Wo   = (const float*)d_in[8];   // (100,200)
  const float* bo   = (const float*)d_in[9];   // (200)
  float* out = (float*)d_out;

  // workspace layout (floats)
  float* ws = (float*)d_ws;
  float*  Gq     = ws;                      // 160000
  float*  baseq  = ws + 160000;             // 400
  float*  c0q    = ws + 160400;             // 400
  float*  c1q    = ws + 160800;             // 400
  float*  WoT    = ws + 161200;             // 20000
  float4* Bfrag  = (float4*)(ws + 181200);  // 6400 float4 = 25600 floats
  int*    idx2   = (int*)(ws + 206800);     // 64000
  int*    qi     = (int*)(ws + 270800);     // 64000
  float2* ccg    = (float2*)(ws + 334800);  // 64000 float2 = 128000 floats
  float*  h_seq  = ws + 462800;             // 6,400,000
  // total: 6,862,800 floats = 27.5 MB

  // A: compress one-hots
  k_compress<<<BT / 4, 256, 0, stream>>>(x, q, idx2, qi);

  // A2: parallel count features
  k_counts<<<TB, 512, 0, stream>>>(idx2, ccg);

  // B: precompute permuted tables + MFMA B-fragments
  int tail_blocks = (TS * TH + 6400 + 511) / 512;        // 52
  k_precompute<<<NCLS + 1 + tail_blocks, 512, 0, stream>>>(Wx, bx, K, lb, Wo, R,
                                                           Gq, baseq, c0q, c1q, WoT, Bfrag);

  // C: sequential LSTM, one block per batch element, 8-wave exact-25 MFMA
  k_lstm<<<TB, BLK, 0, stream>>>(idx2, Gq, baseq, c0q, c1q, Bfrag, ccg, h_seq);

  // D: gather + dot + sigmoid
  k_out<<<BT / 4, 256, 0, stream>>>(h_seq, WoT, bo, qi, out);
}